// Round 1
// baseline (865.345 us; speedup 1.0000x reference)
//
#include <hip/hip_runtime.h>
#include <hip/hip_bf16.h>
#include <stdint.h>

#define D_IN 256
#define NEG 0.2f

typedef unsigned short bf16_t;

__device__ __forceinline__ bf16_t f2bf(float f) {
  unsigned int u = __float_as_uint(f);
  unsigned int r = u + 0x7FFFu + ((u >> 16) & 1u);   // RNE
  return (bf16_t)(r >> 16);
}
__device__ __forceinline__ void ld4bf(const bf16_t* p, float* f) {
  uint2 u = *(const uint2*)p;
  f[0] = __uint_as_float(u.x << 16);
  f[1] = __uint_as_float(u.x & 0xFFFF0000u);
  f[2] = __uint_as_float(u.y << 16);
  f[3] = __uint_as_float(u.y & 0xFFFF0000u);
}

// ---------------- CSR build ----------------
__global__ void k_zero(int* __restrict__ a, int n) {
  int i = blockIdx.x * 256 + threadIdx.x;
  if (i < n) a[i] = 0;
}

__global__ void k_hist(const int* __restrict__ dst, int E, int* __restrict__ deg) {
  int e = blockIdx.x * 256 + threadIdx.x;
  if (e < E) atomicAdd(&deg[dst[e]], 1);
}

// block scans 1024 elements (256 thr x 4); writes within-chunk exclusive prefix + chunk total
__global__ __launch_bounds__(256) void k_scanA(const int* __restrict__ deg,
                                               int* __restrict__ offs,
                                               int* __restrict__ bsum, int N) {
  __shared__ int sh[256];
  int t = threadIdx.x;
  int base = blockIdx.x * 1024 + t * 4;
  int v[4];
#pragma unroll
  for (int q = 0; q < 4; q++) v[q] = (base + q < N) ? deg[base + q] : 0;
  int ls = v[0] + v[1] + v[2] + v[3];
  sh[t] = ls;
  __syncthreads();
  for (int ofs = 1; ofs < 256; ofs <<= 1) {
    int x = (t >= ofs) ? sh[t - ofs] : 0;
    __syncthreads();
    sh[t] += x;
    __syncthreads();
  }
  int run = sh[t] - ls;  // exclusive
#pragma unroll
  for (int q = 0; q < 4; q++) {
    if (base + q < N) offs[base + q] = run;
    run += v[q];
  }
  if (t == 255) bsum[blockIdx.x] = sh[255];
}

__global__ __launch_bounds__(128) void k_scanB(int* __restrict__ bsum, int* __restrict__ offs,
                                               int nb, int E, int N) {
  __shared__ int sh[128];
  int t = threadIdx.x;
  int v = (t < nb) ? bsum[t] : 0;
  sh[t] = v;
  __syncthreads();
  for (int ofs = 1; ofs < 128; ofs <<= 1) {
    int x = (t >= ofs) ? sh[t - ofs] : 0;
    __syncthreads();
    sh[t] += x;
    __syncthreads();
  }
  if (t < nb) bsum[t] = sh[t] - v;  // exclusive block offsets
  if (t == 0) offs[N] = E;
}

__global__ __launch_bounds__(256) void k_scanC(int* __restrict__ offs, int* __restrict__ cursor,
                                               const int* __restrict__ bsum, int N) {
  int t = threadIdx.x;
  int base = blockIdx.x * 1024 + t * 4;
  int add = bsum[blockIdx.x];
#pragma unroll
  for (int q = 0; q < 4; q++) {
    int i = base + q;
    if (i < N) {
      int o = offs[i] + add;
      offs[i] = o;
      cursor[i] = o;
    }
  }
}

__global__ void k_scatter(const int* __restrict__ src, const int* __restrict__ dst, int E,
                          int* __restrict__ cursor, int* __restrict__ csr) {
  int e = blockIdx.x * 256 + threadIdx.x;
  if (e < E) {
    int pos = atomicAdd(&cursor[dst[e]], 1);
    csr[pos] = src[e];
  }
}

// ---------------- GEMM: xl = emb@Wl, xr = emb@Wr (fp32 compute, bf16 store) ----------------
// 64x128 tile, KT=32, 256 threads, 4x8 microtile
__global__ __launch_bounds__(256) void k_gemm(const float* __restrict__ emb,
                                              const float* __restrict__ Wl,
                                              const float* __restrict__ Wr,
                                              bf16_t* __restrict__ xl,
                                              bf16_t* __restrict__ xr, int N) {
  __shared__ float As[32][68];   // [k][row], padded
  __shared__ float Bs[32][132];  // [k][col], padded
  const int tid = threadIdx.x;
  const int row0 = blockIdx.x * 64;
  const int nt = blockIdx.y;  // 0,1 -> Wl ; 2,3 -> Wr
  const float* W = (nt < 2) ? Wl : Wr;
  bf16_t* dst = (nt < 2) ? xl : xr;
  const int c0 = (nt & 1) * 128;

  const int tx = tid & 15, ty = tid >> 4;
  const int rA = tid >> 2, kq = (tid & 3) * 8;
  const int cB = (tid & 31) * 4, kB = tid >> 5;
  const int arow = row0 + rA;
  const bool aok = arow < N;

  float acc[4][8];
#pragma unroll
  for (int r = 0; r < 4; r++)
#pragma unroll
    for (int c = 0; c < 8; c++) acc[r][c] = 0.f;

  for (int k0 = 0; k0 < 256; k0 += 32) {
    float4 a0 = make_float4(0, 0, 0, 0), a1 = a0;
    if (aok) {
      a0 = *(const float4*)(emb + (size_t)arow * 256 + k0 + kq);
      a1 = *(const float4*)(emb + (size_t)arow * 256 + k0 + kq + 4);
    }
    float4 b0 = *(const float4*)(W + (size_t)(k0 + kB) * 256 + c0 + cB);
    float4 b1 = *(const float4*)(W + (size_t)(k0 + kB + 8) * 256 + c0 + cB);
    float4 b2 = *(const float4*)(W + (size_t)(k0 + kB + 16) * 256 + c0 + cB);
    float4 b3 = *(const float4*)(W + (size_t)(k0 + kB + 24) * 256 + c0 + cB);
    __syncthreads();
    As[kq + 0][rA] = a0.x; As[kq + 1][rA] = a0.y; As[kq + 2][rA] = a0.z; As[kq + 3][rA] = a0.w;
    As[kq + 4][rA] = a1.x; As[kq + 5][rA] = a1.y; As[kq + 6][rA] = a1.z; As[kq + 7][rA] = a1.w;
    *(float4*)&Bs[kB][cB] = b0;
    *(float4*)&Bs[kB + 8][cB] = b1;
    *(float4*)&Bs[kB + 16][cB] = b2;
    *(float4*)&Bs[kB + 24][cB] = b3;
    __syncthreads();
#pragma unroll
    for (int kk = 0; kk < 32; kk++) {
      float4 a = *(const float4*)&As[kk][ty * 4];
      float4 p = *(const float4*)&Bs[kk][tx * 4];
      float4 q4 = *(const float4*)&Bs[kk][64 + tx * 4];
      float ar[4] = {a.x, a.y, a.z, a.w};
      float bc[8] = {p.x, p.y, p.z, p.w, q4.x, q4.y, q4.z, q4.w};
#pragma unroll
      for (int r = 0; r < 4; r++)
#pragma unroll
        for (int c = 0; c < 8; c++) acc[r][c] = fmaf(ar[r], bc[c], acc[r][c]);
    }
  }

#pragma unroll
  for (int r = 0; r < 4; r++) {
    int row = row0 + ty * 4 + r;
    if (row < N) {
      ushort4 o0, o1;
      o0.x = f2bf(acc[r][0]); o0.y = f2bf(acc[r][1]); o0.z = f2bf(acc[r][2]); o0.w = f2bf(acc[r][3]);
      o1.x = f2bf(acc[r][4]); o1.y = f2bf(acc[r][5]); o1.z = f2bf(acc[r][6]); o1.w = f2bf(acc[r][7]);
      *(ushort4*)(dst + (size_t)row * 256 + c0 + tx * 4) = o0;
      *(ushort4*)(dst + (size_t)row * 256 + c0 + 64 + tx * 4) = o1;
    }
  }
}

// ---------------- fused edge scores + online softmax + aggregation ----------------
// one wave per dst node; lane = (head = lane>>4) x (4-channel group = lane&15)
__global__ __launch_bounds__(256) void k_edge(const bf16_t* __restrict__ xl,
                                              const bf16_t* __restrict__ xr,
                                              const int* __restrict__ offs,
                                              const int* __restrict__ csr,
                                              const float* __restrict__ att,
                                              const float* __restrict__ bias,
                                              float* __restrict__ out, int N) {
  const int wv = threadIdx.x >> 6;
  const int lane = threadIdx.x & 63;
  const int i = blockIdx.x * 4 + wv;
  if (i >= N) return;
  const int cbase = (lane >> 4) * 64 + (lane & 15) * 4;

  const float4 avv = *(const float4*)(att + cbase);
  const float av[4] = {avv.x, avv.y, avv.z, avv.w};
  float xrv[4], xlv[4];
  ld4bf(xr + (size_t)i * 256 + cbase, xrv);
  ld4bf(xl + (size_t)i * 256 + cbase, xlv);

  // self-loop initializes the online softmax state
  float part = 0.f;
#pragma unroll
  for (int q = 0; q < 4; q++) {
    float t = xlv[q] + xrv[q];
    t = fmaxf(t, NEG * t);  // leaky_relu
    part = fmaf(av[q], t, part);
  }
  part += __shfl_xor(part, 1);
  part += __shfl_xor(part, 2);
  part += __shfl_xor(part, 4);
  part += __shfl_xor(part, 8);

  float m = part, d = 1.f;
  float acc[4] = {xlv[0], xlv[1], xlv[2], xlv[3]};

  const int kend = offs[i + 1];
  for (int k = offs[i]; k < kend; ++k) {
    int j = csr[k];
    ld4bf(xl + (size_t)j * 256 + cbase, xlv);
    part = 0.f;
#pragma unroll
    for (int q = 0; q < 4; q++) {
      float t = xlv[q] + xrv[q];
      t = fmaxf(t, NEG * t);
      part = fmaf(av[q], t, part);
    }
    part += __shfl_xor(part, 1);
    part += __shfl_xor(part, 2);
    part += __shfl_xor(part, 4);
    part += __shfl_xor(part, 8);
    float nm = fmaxf(m, part);
    float ea = __expf(m - nm);
    float eb = __expf(part - nm);
    d = fmaf(d, ea, eb);
#pragma unroll
    for (int q = 0; q < 4; q++) acc[q] = fmaf(acc[q], ea, eb * xlv[q]);
    m = nm;
  }

  float inv = 0.25f / d;  // 1/denom * mean-over-heads
  float v[4];
#pragma unroll
  for (int q = 0; q < 4; q++) v[q] = acc[q] * inv;
#pragma unroll
  for (int q = 0; q < 4; q++) {
    v[q] += __shfl_xor(v[q], 16);
    v[q] += __shfl_xor(v[q], 32);
  }
  if ((lane >> 4) == 0) {
    const float4 bq = *(const float4*)(bias + (lane & 15) * 4);
    const float bb[4] = {bq.x, bq.y, bq.z, bq.w};
    float o[4];
#pragma unroll
    for (int q = 0; q < 4; q++) {
      float x = v[q] + bb[q];
      o[q] = x > 0.f ? x : (__expf(x) - 1.f);  // elu
    }
    *(float4*)(out + (size_t)i * 64 + (lane & 15) * 4) = make_float4(o[0], o[1], o[2], o[3]);
  }
}

extern "C" void kernel_launch(void* const* d_in, const int* in_sizes, int n_in,
                              void* d_out, int out_size, void* d_ws, size_t ws_size,
                              hipStream_t stream) {
  const int* edge = (const int*)d_in[1];   // [2][E] : row0 = src, row1 = dst
  const float* emb = (const float*)d_in[2];
  const float* Wl = (const float*)d_in[3];
  const float* Wr = (const float*)d_in[4];
  const float* att = (const float*)d_in[5];
  const float* bias = (const float*)d_in[6];
  float* out = (float*)d_out;

  const int E = in_sizes[1] / 2;
  const int N = in_sizes[2] / D_IN;
  const int* src = edge;
  const int* dst = edge + E;

  // workspace carve (aligned)
  char* w = (char*)d_ws;
  bf16_t* xl = (bf16_t*)w;      w += (size_t)N * 256 * 2;
  bf16_t* xr = (bf16_t*)w;      w += (size_t)N * 256 * 2;
  int* offs = (int*)w;          w += ((size_t)N + 64) * 4;
  int* cursor = (int*)w;        w += ((size_t)N + 64) * 4;  // doubles as deg histogram
  int* bsum = (int*)w;          w += 1024;
  int* csr = (int*)w;           w += (size_t)E * 4;

  const int nb = (N + 1023) / 1024;

  hipLaunchKernelGGL(k_zero, dim3((N + 255) / 256), dim3(256), 0, stream, cursor, N);
  hipLaunchKernelGGL(k_hist, dim3((E + 255) / 256), dim3(256), 0, stream, dst, E, cursor);
  hipLaunchKernelGGL(k_scanA, dim3(nb), dim3(256), 0, stream, cursor, offs, bsum, N);
  hipLaunchKernelGGL(k_scanB, dim3(1), dim3(128), 0, stream, bsum, offs, nb, E, N);
  hipLaunchKernelGGL(k_scanC, dim3(nb), dim3(256), 0, stream, offs, cursor, bsum, N);
  hipLaunchKernelGGL(k_scatter, dim3((E + 255) / 256), dim3(256), 0, stream, src, dst, E, cursor, csr);

  hipLaunchKernelGGL(k_gemm, dim3((N + 63) / 64, 4), dim3(256), 0, stream, emb, Wl, Wr, xl, xr, N);
  hipLaunchKernelGGL(k_edge, dim3((N + 3) / 4), dim3(256), 0, stream, xl, xr, offs, csr, att, bias, out, N);
}

// Round 2
// 558.733 us; speedup vs baseline: 1.5488x; 1.5488x over previous
//
#include <hip/hip_runtime.h>
#include <hip/hip_bf16.h>
#include <stdint.h>

#define D_IN 256
#define NEG 0.2f

typedef unsigned short bf16_t;
typedef __attribute__((ext_vector_type(8))) short bfrag;   // 8 bf16 = 4 VGPR
typedef __attribute__((ext_vector_type(4))) float ffrag;   // MFMA C/D

__device__ __forceinline__ bf16_t f2bf(float f) {
  unsigned int u = __float_as_uint(f);
  unsigned int r = u + 0x7FFFu + ((u >> 16) & 1u);   // RNE
  return (bf16_t)(r >> 16);
}
__device__ __forceinline__ unsigned int pk2(float a, float b) {
  return (unsigned int)f2bf(a) | ((unsigned int)f2bf(b) << 16);
}
__device__ __forceinline__ void ld4bf(const bf16_t* p, float* f) {
  uint2 u = *(const uint2*)p;
  f[0] = __uint_as_float(u.x << 16);
  f[1] = __uint_as_float(u.x & 0xFFFF0000u);
  f[2] = __uint_as_float(u.y << 16);
  f[3] = __uint_as_float(u.y & 0xFFFF0000u);
}

// ---------------- CSR build ----------------
__global__ void k_zero(int* __restrict__ a, int n) {
  int i = blockIdx.x * 256 + threadIdx.x;
  if (i < n) a[i] = 0;
}

__global__ void k_hist(const int* __restrict__ dst, int E, int* __restrict__ deg) {
  int e = blockIdx.x * 256 + threadIdx.x;
  if (e < E) atomicAdd(&deg[dst[e]], 1);
}

__global__ __launch_bounds__(256) void k_scanA(const int* __restrict__ deg,
                                               int* __restrict__ offs,
                                               int* __restrict__ bsum, int N) {
  __shared__ int sh[256];
  int t = threadIdx.x;
  int base = blockIdx.x * 1024 + t * 4;
  int v[4];
#pragma unroll
  for (int q = 0; q < 4; q++) v[q] = (base + q < N) ? deg[base + q] : 0;
  int ls = v[0] + v[1] + v[2] + v[3];
  sh[t] = ls;
  __syncthreads();
  for (int ofs = 1; ofs < 256; ofs <<= 1) {
    int x = (t >= ofs) ? sh[t - ofs] : 0;
    __syncthreads();
    sh[t] += x;
    __syncthreads();
  }
  int run = sh[t] - ls;
#pragma unroll
  for (int q = 0; q < 4; q++) {
    if (base + q < N) offs[base + q] = run;
    run += v[q];
  }
  if (t == 255) bsum[blockIdx.x] = sh[255];
}

__global__ __launch_bounds__(128) void k_scanB(int* __restrict__ bsum, int* __restrict__ offs,
                                               int nb, int E, int N) {
  __shared__ int sh[128];
  int t = threadIdx.x;
  int v = (t < nb) ? bsum[t] : 0;
  sh[t] = v;
  __syncthreads();
  for (int ofs = 1; ofs < 128; ofs <<= 1) {
    int x = (t >= ofs) ? sh[t - ofs] : 0;
    __syncthreads();
    sh[t] += x;
    __syncthreads();
  }
  if (t < nb) bsum[t] = sh[t] - v;
  if (t == 0) offs[N] = E;
}

__global__ __launch_bounds__(256) void k_scanC(int* __restrict__ offs, int* __restrict__ cursor,
                                               const int* __restrict__ bsum, int N) {
  int t = threadIdx.x;
  int base = blockIdx.x * 1024 + t * 4;
  int add = bsum[blockIdx.x];
#pragma unroll
  for (int q = 0; q < 4; q++) {
    int i = base + q;
    if (i < N) {
      int o = offs[i] + add;
      offs[i] = o;
      cursor[i] = o;
    }
  }
}

__global__ void k_scatter(const int* __restrict__ src, const int* __restrict__ dst, int E,
                          int* __restrict__ cursor, int* __restrict__ csr) {
  int e = blockIdx.x * 256 + threadIdx.x;
  if (e < E) {
    int pos = atomicAdd(&cursor[dst[e]], 1);
    csr[pos] = src[e];
  }
}

// ---------------- W transpose + bf16 convert: Wt[w][col][k] = W_w[k][col] ----------------
__global__ void k_wt(const float* __restrict__ Wl, const float* __restrict__ Wr,
                     bf16_t* __restrict__ Wt) {
  int gid = blockIdx.x * 256 + threadIdx.x;   // 2*256*256 total
  int w = gid >> 16;
  int c = (gid >> 8) & 255;
  int k = gid & 255;
  const float* W = w ? Wr : Wl;
  Wt[gid] = f2bf(W[k * 256 + c]);
}

// ---------------- MFMA GEMM: {xl,xr} = emb @ {Wl,Wr}, fp32 in, bf16 out ----------------
// 128x128 tile, BK=32, 256 threads = 4 waves, each wave 64x64 via 4x4 of 16x16x32
__global__ __launch_bounds__(256) void k_gemm_mfma(const float* __restrict__ emb,
                                                   const bf16_t* __restrict__ Wt,
                                                   bf16_t* __restrict__ xl,
                                                   bf16_t* __restrict__ xr, int N) {
  __shared__ bf16_t As[128][40];  // [row][k], stride 80B: frag reads 2-way-conflict max
  __shared__ bf16_t Bs[128][40];  // [col][k]

  const int tid = threadIdx.x;
  const int row0 = blockIdx.x * 128;
  const int nt = blockIdx.y;           // 0,1 -> Wl ; 2,3 -> Wr
  const bf16_t* Wp = Wt + (size_t)(nt >> 1) * 65536;
  bf16_t* dst = (nt < 2) ? xl : xr;
  const int c0 = (nt & 1) * 128;

  const int wave = tid >> 6, lane = tid & 63;
  const int m0w = (wave & 1) * 64, n0w = (wave >> 1) * 64;
  const int fr = lane & 15;            // frag row/col index
  const int aq = (lane >> 4) * 8;      // frag k offset

  // staging coords: 2 threads per row/col, 16 elements each
  const int srow = tid >> 1, sseg = (tid & 1) * 16;
  const int grow = row0 + srow;
  const bool aok = grow < N;
  const float* ap = emb + (size_t)grow * 256 + sseg;
  const bf16_t* bp = Wp + (size_t)(c0 + srow) * 256 + sseg;

  ffrag acc[4][4];
#pragma unroll
  for (int mi = 0; mi < 4; mi++)
#pragma unroll
    for (int ni = 0; ni < 4; ni++) acc[mi][ni] = (ffrag)0.f;

  for (int k0 = 0; k0 < 256; k0 += 32) {
    float4 f0 = make_float4(0, 0, 0, 0), f1 = f0, f2 = f0, f3 = f0;
    if (aok) {
      f0 = *(const float4*)(ap + k0);
      f1 = *(const float4*)(ap + k0 + 4);
      f2 = *(const float4*)(ap + k0 + 8);
      f3 = *(const float4*)(ap + k0 + 12);
    }
    uint4 bv0 = *(const uint4*)(bp + k0);
    uint4 bv1 = *(const uint4*)(bp + k0 + 8);
    __syncthreads();
    uint4 p0, p1;
    p0.x = pk2(f0.x, f0.y); p0.y = pk2(f0.z, f0.w);
    p0.z = pk2(f1.x, f1.y); p0.w = pk2(f1.z, f1.w);
    p1.x = pk2(f2.x, f2.y); p1.y = pk2(f2.z, f2.w);
    p1.z = pk2(f3.x, f3.y); p1.w = pk2(f3.z, f3.w);
    *(uint4*)&As[srow][sseg] = p0;
    *(uint4*)&As[srow][sseg + 8] = p1;
    *(uint4*)&Bs[srow][sseg] = bv0;
    *(uint4*)&Bs[srow][sseg + 8] = bv1;
    __syncthreads();

    bfrag af[4], bf[4];
#pragma unroll
    for (int mi = 0; mi < 4; mi++) af[mi] = *(const bfrag*)&As[m0w + mi * 16 + fr][aq];
#pragma unroll
    for (int ni = 0; ni < 4; ni++) bf[ni] = *(const bfrag*)&Bs[n0w + ni * 16 + fr][aq];
#pragma unroll
    for (int mi = 0; mi < 4; mi++)
#pragma unroll
      for (int ni = 0; ni < 4; ni++)
        acc[mi][ni] = __builtin_amdgcn_mfma_f32_16x16x32_bf16(af[mi], bf[ni], acc[mi][ni], 0, 0, 0);
  }

  // C/D: col = lane&15, row = (lane>>4)*4 + r
  const int rbase = m0w + (lane >> 4) * 4;
#pragma unroll
  for (int mi = 0; mi < 4; mi++) {
#pragma unroll
    for (int ni = 0; ni < 4; ni++) {
      int col = c0 + n0w + ni * 16 + fr;
#pragma unroll
      for (int r = 0; r < 4; r++) {
        int row = row0 + rbase + mi * 16 + r;
        if (row < N) dst[(size_t)row * 256 + col] = f2bf(acc[mi][ni][r]);
      }
    }
  }
}

// ---------------- fused edge scores + online softmax + aggregation ----------------
// one wave per dst node; lane = (head = lane>>4) x (4-channel group = lane&15)
__device__ __forceinline__ float wred16(float p) {
  p += __shfl_xor(p, 1);
  p += __shfl_xor(p, 2);
  p += __shfl_xor(p, 4);
  p += __shfl_xor(p, 8);
  return p;
}

__global__ __launch_bounds__(256) void k_edge(const bf16_t* __restrict__ xl,
                                              const bf16_t* __restrict__ xr,
                                              const int* __restrict__ offs,
                                              const int* __restrict__ csr,
                                              const float* __restrict__ att,
                                              const float* __restrict__ bias,
                                              float* __restrict__ out, int N) {
  const int wv = threadIdx.x >> 6;
  const int lane = threadIdx.x & 63;
  const int i = blockIdx.x * 4 + wv;
  if (i >= N) return;
  const int cbase = (lane >> 4) * 64 + (lane & 15) * 4;

  const float4 avv = *(const float4*)(att + cbase);
  const float av[4] = {avv.x, avv.y, avv.z, avv.w};
  float xrv[4], xlv[4];
  ld4bf(xr + (size_t)i * 256 + cbase, xrv);
  ld4bf(xl + (size_t)i * 256 + cbase, xlv);

  // self-loop initializes online softmax state
  float part = 0.f;
#pragma unroll
  for (int q = 0; q < 4; q++) {
    float t = xlv[q] + xrv[q];
    t = fmaxf(t, NEG * t);
    part = fmaf(av[q], t, part);
  }
  float m = wred16(part), d = 1.f;
  float acc[4] = {xlv[0], xlv[1], xlv[2], xlv[3]};

  int k = offs[i];
  const int kend = offs[i + 1];

  // batch-4 flash-style loop: 4 independent gathers + one rescale per batch
  for (; k + 4 <= kend; k += 4) {
    int j0 = csr[k], j1 = csr[k + 1], j2 = csr[k + 2], j3 = csr[k + 3];
    float x0[4], x1[4], x2[4], x3[4];
    ld4bf(xl + (size_t)j0 * 256 + cbase, x0);
    ld4bf(xl + (size_t)j1 * 256 + cbase, x1);
    ld4bf(xl + (size_t)j2 * 256 + cbase, x2);
    ld4bf(xl + (size_t)j3 * 256 + cbase, x3);
    float p0 = 0.f, p1 = 0.f, p2 = 0.f, p3 = 0.f;
#pragma unroll
    for (int q = 0; q < 4; q++) {
      float t0 = x0[q] + xrv[q], t1 = x1[q] + xrv[q];
      float t2 = x2[q] + xrv[q], t3 = x3[q] + xrv[q];
      t0 = fmaxf(t0, NEG * t0); t1 = fmaxf(t1, NEG * t1);
      t2 = fmaxf(t2, NEG * t2); t3 = fmaxf(t3, NEG * t3);
      p0 = fmaf(av[q], t0, p0); p1 = fmaf(av[q], t1, p1);
      p2 = fmaf(av[q], t2, p2); p3 = fmaf(av[q], t3, p3);
    }
    float s0 = wred16(p0), s1 = wred16(p1), s2 = wred16(p2), s3 = wred16(p3);
    float nm = fmaxf(m, fmaxf(fmaxf(s0, s1), fmaxf(s2, s3)));
    float ea = __expf(m - nm);
    float e0 = __expf(s0 - nm), e1 = __expf(s1 - nm);
    float e2 = __expf(s2 - nm), e3 = __expf(s3 - nm);
    d = fmaf(d, ea, (e0 + e1) + (e2 + e3));
#pragma unroll
    for (int q = 0; q < 4; q++)
      acc[q] = fmaf(acc[q], ea,
                    fmaf(e0, x0[q], e1 * x1[q]) + fmaf(e2, x2[q], e3 * x3[q]));
    m = nm;
  }
  // remainder
  for (; k < kend; ++k) {
    int j = csr[k];
    ld4bf(xl + (size_t)j * 256 + cbase, xlv);
    float p = 0.f;
#pragma unroll
    for (int q = 0; q < 4; q++) {
      float t = xlv[q] + xrv[q];
      t = fmaxf(t, NEG * t);
      p = fmaf(av[q], t, p);
    }
    float s = wred16(p);
    float nm = fmaxf(m, s);
    float ea = __expf(m - nm);
    float eb = __expf(s - nm);
    d = fmaf(d, ea, eb);
#pragma unroll
    for (int q = 0; q < 4; q++) acc[q] = fmaf(acc[q], ea, eb * xlv[q]);
    m = nm;
  }

  float inv = 0.25f / d;
  float v[4];
#pragma unroll
  for (int q = 0; q < 4; q++) v[q] = acc[q] * inv;
#pragma unroll
  for (int q = 0; q < 4; q++) {
    v[q] += __shfl_xor(v[q], 16);
    v[q] += __shfl_xor(v[q], 32);
  }
  if ((lane >> 4) == 0) {
    const float4 bq = *(const float4*)(bias + (lane & 15) * 4);
    const float bb[4] = {bq.x, bq.y, bq.z, bq.w};
    float o[4];
#pragma unroll
    for (int q = 0; q < 4; q++) {
      float x = v[q] + bb[q];
      o[q] = x > 0.f ? x : (__expf(x) - 1.f);
    }
    *(float4*)(out + (size_t)i * 64 + (lane & 15) * 4) = make_float4(o[0], o[1], o[2], o[3]);
  }
}

extern "C" void kernel_launch(void* const* d_in, const int* in_sizes, int n_in,
                              void* d_out, int out_size, void* d_ws, size_t ws_size,
                              hipStream_t stream) {
  const int* edge = (const int*)d_in[1];   // [2][E] : row0 = src, row1 = dst
  const float* emb = (const float*)d_in[2];
  const float* Wl = (const float*)d_in[3];
  const float* Wr = (const float*)d_in[4];
  const float* att = (const float*)d_in[5];
  const float* bias = (const float*)d_in[6];
  float* out = (float*)d_out;

  const int E = in_sizes[1] / 2;
  const int N = in_sizes[2] / D_IN;
  const int* src = edge;
  const int* dst = edge + E;

  // workspace carve
  char* w = (char*)d_ws;
  bf16_t* xl = (bf16_t*)w;      w += (size_t)N * 256 * 2;
  bf16_t* xr = (bf16_t*)w;      w += (size_t)N * 256 * 2;
  bf16_t* Wt = (bf16_t*)w;      w += (size_t)2 * 256 * 256 * 2;
  int* offs = (int*)w;          w += ((size_t)N + 64) * 4;
  int* cursor = (int*)w;        w += ((size_t)N + 64) * 4;
  int* bsum = (int*)w;          w += 1024;
  int* csr = (int*)w;           w += (size_t)E * 4;

  const int nb = (N + 1023) / 1024;

  hipLaunchKernelGGL(k_zero, dim3((N + 255) / 256), dim3(256), 0, stream, cursor, N);
  hipLaunchKernelGGL(k_hist, dim3((E + 255) / 256), dim3(256), 0, stream, dst, E, cursor);
  hipLaunchKernelGGL(k_scanA, dim3(nb), dim3(256), 0, stream, cursor, offs, bsum, N);
  hipLaunchKernelGGL(k_scanB, dim3(1), dim3(128), 0, stream, bsum, offs, nb, E, N);
  hipLaunchKernelGGL(k_scanC, dim3(nb), dim3(256), 0, stream, offs, cursor, bsum, N);
  hipLaunchKernelGGL(k_scatter, dim3((E + 255) / 256), dim3(256), 0, stream, src, dst, E, cursor, csr);

  hipLaunchKernelGGL(k_wt, dim3(512), dim3(256), 0, stream, Wl, Wr, Wt);
  hipLaunchKernelGGL(k_gemm_mfma, dim3((N + 127) / 128, 4), dim3(256), 0, stream, emb, Wt, xl, xr, N);
  hipLaunchKernelGGL(k_edge, dim3((N + 3) / 4), dim3(256), 0, stream, xl, xr, offs, csr, att, bias, out, N);
}